// Round 6
// baseline (323.087 us; speedup 1.0000x reference)
//
#include <hip/hip_runtime.h>
#include <utility>

using u16 = unsigned short;
using u32 = unsigned int;

typedef float  f32x4   __attribute__((ext_vector_type(4)));
typedef float  f32x16  __attribute__((ext_vector_type(16)));
typedef __bf16 bf16x8  __attribute__((ext_vector_type(8)));

#define DI __device__ __forceinline__

// ------------------------------------------------------------------
// Monomial basis under the +8 rotation group (for 32x32x16 MFMA).
// Monomials over x[0..15]: cubic (816), quadratic (136), linear (16).
// Group action: rotation by +8q mod 16 (q=0..1).  Cubic orbits all size
// 2 (parity: 3*8=24 != 0 mod 16) -> 408 reps; quad: 8 fixed orbits
// {a,a+8} + 64 size-2 -> 72 reps (8 dup slots stay null); linear -> 8
// reps.  408+72+8 = 488 = 61 chunks * 8 exactly (no padding).
// Feature slot f = chunk*16 + q*8 + j  <->  rep r = chunk*8 + j,
// monomial = rot_{8q}(rep[r]).  Lane half q = lane>>5 holds x rotated by
// 8q at the address level, so all lanes run identical compile-time code.
// ------------------------------------------------------------------
struct RepT { unsigned char a, b, c, t; };   // t: 3=cubic 2=quad 1=linear 0=null
struct Tables8 {
  RepT rep[488];        // compile-time rep list for feature templates
  RepT slotmono[976];   // per feature-slot: SORTED monomial (prep gather); t=0 if dup
  int n3, n2, n1;
};

constexpr int csort3key(int w, int x, int i) {
  int a = w, b = x, c = i, t = 0;
  if (a > b) { t = a; a = b; b = t; }
  if (b > c) { t = b; b = c; c = t; }
  if (a > b) { t = a; a = b; b = t; }
  return (a << 8) | (b << 4) | c;
}
constexpr int csort2key(int a, int b) { return a <= b ? ((a << 4) | b) : ((b << 4) | a); }

constexpr Tables8 build_tables8() {
  Tables8 T = {};
  bool used3[4096] = {};
  bool used2[256] = {};
  int nr = 0;
  // cubic multisets a<=b<=c, canonical = lex-min of {self, +8 rotation}
  for (int a = 0; a < 16; a++) for (int b = a; b < 16; b++) for (int c = b; c < 16; c++) {
    const int key  = (a << 8) | (b << 4) | c;
    const int rkey = csort3key((a + 8) & 15, (b + 8) & 15, (c + 8) & 15);
    if (rkey < key) continue;                 // partner is the canonical one
    for (int q = 0; q < 2; q++) {
      const int kk = q ? rkey : key;
      if (!used3[kk]) {
        used3[kk] = true;
        const int f = (nr >> 3) * 16 + q * 8 + (nr & 7);
        T.slotmono[f].a = (unsigned char)(kk >> 8);
        T.slotmono[f].b = (unsigned char)((kk >> 4) & 15);
        T.slotmono[f].c = (unsigned char)(kk & 15);
        T.slotmono[f].t = 3;
      }
    }
    T.rep[nr].a = (unsigned char)a; T.rep[nr].b = (unsigned char)b;
    T.rep[nr].c = (unsigned char)c; T.rep[nr].t = 3; nr++;
  }
  T.n3 = nr;
  // quadratic multisets a<=b
  for (int a = 0; a < 16; a++) for (int b = a; b < 16; b++) {
    const int key  = (a << 4) | b;
    const int rkey = csort2key((a + 8) & 15, (b + 8) & 15);
    if (rkey < key) continue;
    for (int q = 0; q < 2; q++) {
      const int kk = q ? rkey : key;
      if (!used2[kk]) {                      // fixed orbits: q=1 slot stays null
        used2[kk] = true;
        const int f = (nr >> 3) * 16 + q * 8 + (nr & 7);
        T.slotmono[f].a = (unsigned char)(kk >> 4);
        T.slotmono[f].b = (unsigned char)(kk & 15);
        T.slotmono[f].c = 0;
        T.slotmono[f].t = 2;
      }
    }
    T.rep[nr].a = (unsigned char)a; T.rep[nr].b = (unsigned char)b;
    T.rep[nr].c = 0; T.rep[nr].t = 2; nr++;
  }
  T.n2 = nr;
  // linear: reps 0..7, orbit {a, a+8}
  for (int a = 0; a < 8; a++) {
    for (int q = 0; q < 2; q++) {
      const int f = (nr >> 3) * 16 + q * 8 + (nr & 7);
      T.slotmono[f].a = (unsigned char)((a + 8 * q) & 15);
      T.slotmono[f].b = 0; T.slotmono[f].c = 0; T.slotmono[f].t = 1;
    }
    T.rep[nr].a = (unsigned char)a; T.rep[nr].b = 0; T.rep[nr].c = 0;
    T.rep[nr].t = 1; nr++;
  }
  T.n1 = nr;
  return T;
}

constexpr Tables8 TT8 = build_tables8();
static_assert(TT8.n3 == 408, "cubic rep count");
static_assert(TT8.n2 == 480, "quad rep count");
static_assert(TT8.n1 == 488, "linear rep count");   // 61 chunks * 8, exact

__device__ const Tables8 g_T8 = build_tables8();   // runtime copy for prep kernel

// dims
#define BN 5888
#define CN 128
#define EN 10
#define NCHUNK 61          // 488 reps / 8; K = 976
#define SPLITC 36          // chunks 0..35 served from LDS, 36..60 from L2
#define GRID 768           // persistent: exactly 3 blocks per CU

DI u16 f2bf(float f) { union { __bf16 h; u16 s; } u; u.h = (__bf16)f; return u.s; }
DI float bf2f(u16 v) { union { u32 u; float f; } w; w.u = ((u32)v) << 16; return w.f; }

// ------------------------------------------------------------------
// prep kernel: ONE dispatch, no memset, no atomics.  One thread per
// packed-fragment u16: gathers its monomial's <=6 distinct U-index
// permutations, sums, converts to bf16, writes coalesced.
// Fragment layout (matches main's A-read exactly):
// uint4 idx = chunk*64 + l; lane l: path = l&31, q = l>>5; u16 j in
// [0,8): feature slot = chunk*16 + q*8 + j.  Paths 28..31 are zero.
// ------------------------------------------------------------------
#define PREP_THREADS (NCHUNK * 64 * 8)     // 31232 u16 = 61 KB

__global__ void prep_kernel(const float* __restrict__ U3, const float* __restrict__ U2,
                            const float* __restrict__ U1, u16* __restrict__ Sfrag16) {
  const int tid = blockIdx.x * 256 + threadIdx.x;
  if (tid >= PREP_THREADS) return;
  const int j = tid & 7, l = (tid >> 3) & 63, chunk = tid >> 9;
  const int path = l & 31, q = l >> 5;
  const RepT m = g_T8.slotmono[chunk * 16 + q * 8 + j];
  float v = 0.f;
  if (m.t == 3 && path < 23) {
    const int a = m.a, b = m.b, d = m.c;
    v = U3[((a * 16 + b) * 16 + d) * 23 + path];
    if (a == b && b == d) {
      // single distinct permutation
    } else if (a == b) {            // (a,a,d): +ada, +daa
      v += U3[((a * 16 + d) * 16 + a) * 23 + path]
         + U3[((d * 16 + a) * 16 + a) * 23 + path];
    } else if (b == d) {            // (a,b,b): +bab, +bba
      v += U3[((b * 16 + a) * 16 + b) * 23 + path]
         + U3[((b * 16 + b) * 16 + a) * 23 + path];
    } else {                        // all distinct: 6 perms
      v += U3[((a * 16 + d) * 16 + b) * 23 + path]
         + U3[((b * 16 + a) * 16 + d) * 23 + path]
         + U3[((b * 16 + d) * 16 + a) * 23 + path]
         + U3[((d * 16 + a) * 16 + b) * 23 + path]
         + U3[((d * 16 + b) * 16 + a) * 23 + path];
    }
  } else if (m.t == 2 && path >= 23 && path < 27) {
    const int k = path - 23, a = m.a, b = m.b;
    v = U2[(a * 16 + b) * 4 + k];
    if (a != b) v += U2[(b * 16 + a) * 4 + k];
  } else if (m.t == 1 && path == 27) {
    v = U1[m.a];
  }
  Sfrag16[tid] = f2bf(v);
}

// ------------------------------------------------------------------
// main kernel (32x32x16 MFMA).  Journal of hard-won constraints:
//  - NEVER demand occupancy beyond the VGPR budget via launch_bounds
//    min-waves (round 0: clamp to 32 VGPR -> 430 MB scratch traffic).
//  - NO sched_barrier (prior round 10: 8x regression).
//  - w-reads block-coalesced once (prior round 5: 990 MB L2 fetch).
//  - Round 2: K-splitting across waves doubles per-wave fixed costs.
//  - Round 3 (best, 103 us): ds_read A-path, VGPR 64; wall ~2x VALU
//    pipe because only ~12-16 waves/CU (61 KB sfrag jailer).
//  - Round 4: full-global A-path -> VGPR 76 (>64 halves wave cap to
//    16/CU) + exposed L2 latency = 120 us.  Worse.
// THIS ROUND: hybrid split 36 LDS + 25 L2 chunks, interleaved.  LDS =
// 36 KB sfrag + 16 KB wbl = 52 KB -> 3 blocks/CU = 24 waves/CU iff
// VGPR <= 85 (expected ~72-80; (512,4) grants 128 so NO spill risk,
// worst case falls back to 16 waves/CU ~= round 3).  PLUS persistent
// blocks: grid = 768 = exactly 3/CU, each block loops ~4 node-pairs;
// S staged ONCE per block; guaranteed steady residency, no tail.
// ------------------------------------------------------------------
template<int R>
DI float featf(const float* xr) {
  constexpr RepT rp = TT8.rep[R];
  if constexpr (rp.t == 3) return xr[rp.a] * xr[rp.b] * xr[rp.c];
  else if constexpr (rp.t == 2) return xr[rp.a] * xr[rp.b];
  else if constexpr (rp.t == 1) return xr[rp.a];
  else return 0.f;
}

template<int C>
DI bf16x8 make_B(const float* xr) {
  bf16x8 r;
  r[0] = (__bf16)featf<C * 8 + 0>(xr);
  r[1] = (__bf16)featf<C * 8 + 1>(xr);
  r[2] = (__bf16)featf<C * 8 + 2>(xr);
  r[3] = (__bf16)featf<C * 8 + 3>(xr);
  r[4] = (__bf16)featf<C * 8 + 4>(xr);
  r[5] = (__bf16)featf<C * 8 + 5>(xr);
  r[6] = (__bf16)featf<C * 8 + 6>(xr);
  r[7] = (__bf16)featf<C * 8 + 7>(xr);
  return r;
}

// A: 32 paths x 16 K fragment.  LDS chunks: B built first (keeps A's
// live range ds_read -> MFMA, round-3 pattern).  Global chunks: A load
// issued first so the compiler can hoist it across earlier MFMAs.
template<int C>
DI void chunk_step(const uint4* sfl, const uint4* __restrict__ sgl,
                   const float* xr, f32x16& acc) {
  if constexpr (C < SPLITC) {
    const bf16x8 B = make_B<C>(xr);
    const bf16x8 A = *reinterpret_cast<const bf16x8*>(sfl + C * 64);
    acc = __builtin_amdgcn_mfma_f32_32x32x16_bf16(A, B, acc, 0, 0, 0);
  } else {
    const bf16x8 A = *reinterpret_cast<const bf16x8*>(sgl + C * 64);
    const bf16x8 B = make_B<C>(xr);
    acc = __builtin_amdgcn_mfma_f32_32x32x16_bf16(A, B, acc, 0, 0, 0);
  }
}

// Interleave order: L0 G36 L1 G37 ... L24 G60 L25..L35 — spreads the 25
// vmem loads between ds_reads so both queues stay fed.
constexpr int chunk_order(int i) {
  return i < 50 ? ((i & 1) ? SPLITC + (i >> 1) : (i >> 1)) : i - 25;
}

template<int... Is>
DI void run_chunks(std::integer_sequence<int, Is...>, const uint4* sfl,
                   const uint4* __restrict__ sgl, const float* xr, f32x16& acc) {
  (chunk_step<chunk_order(Is)>(sfl, sgl, xr, acc), ...);
}

// xr[v] = x[pair][(v + 8q) & 15] via float4-group rotation (2 groups = 8)
DI void load_xr(const float* __restrict__ x, int pair, int q, float* xr) {
  const float* base = x + pair * 16;
#pragma unroll
  for (int u = 0; u < 4; u++) {
    const int g = (u + 2 * q) & 3;
    const float4 v = *(const float4*)(base + g * 4);
    xr[u * 4 + 0] = v.x;
    xr[u * 4 + 1] = v.y;
    xr[u * 4 + 2] = v.z;
    xr[u * 4 + 3] = v.w;
  }
}

// Persistent 512-thread blocks: 8 waves = 2 nodes per iteration.
// LDS = 36 KB sfrag + 16 KB wbl = 53248 B -> 3 blocks/CU.  (512,4)
// grants a 128-VGPR budget: no spill possible; 24 waves/CU if the
// allocator stays <= 85 (expected ~72-80).
__global__ __launch_bounds__(512, 4) void main_kernel(
    const float* __restrict__ x, const float* __restrict__ y,
    const float* __restrict__ w3, const float* __restrict__ w2, const float* __restrict__ w1,
    const uint4* __restrict__ Sfrag, float* __restrict__ out)
{
  __shared__ uint4 sfrag[SPLITC * 64];         // 36 KB: LDS-resident chunks
  __shared__ u16  wbl[2][32 * 128];            // 16 KB: WB[path][c] bf16, per node
  const int tid = threadIdx.x;

  // stage the LDS half of S ONCE per persistent block (straight copy);
  // first in-loop __syncthreads() covers visibility before first use.
  for (int idx = tid; idx < SPLITC * 64; idx += 512) sfrag[idx] = Sfrag[idx];

  const int nl = tid >> 8;                     // node-local index 0/1 (WB phase)
  const int w = tid >> 6, wn = w & 3, nw = w >> 2;   // MFMA phase decode
  const int lane = tid & 63, col = lane & 31, q = lane >> 5;
  const uint4* sfl = sfrag + lane;
  const uint4* __restrict__ sgl = Sfrag + lane;      // per-lane 16 B slice (L2)

  for (int g = blockIdx.x; g < BN / 2; g += GRID) {
    const int node0 = g * 2;

    // per-node WB = y[b] @ concat(w3,w2,w1).  tl = tid&255 -> p = tl>>3
    // (32 paths), c-16-seg = (tl&7)*16.  Rows 28..31: zeros (branchless
    // epilogue).  Coalesced w-reads ONCE per node (round 5 lesson).
    {
      const int bnode = node0 + nl;
      const int tl = tid & 255;
      const int p  = tl >> 3;
      const int c0 = (tl & 7) * 16;
      float yv[EN];
#pragma unroll
      for (int e = 0; e < EN; e++) yv[e] = y[bnode * EN + e];
      float acc[16];
#pragma unroll
      for (int m = 0; m < 16; m++) acc[m] = 0.f;
      const float* wsrc = nullptr; int stride = 0;
      if (p < 23)       { wsrc = w3 + p * 128;        stride = 23 * 128; }
      else if (p < 27)  { wsrc = w2 + (p - 23) * 128; stride = 4 * 128; }
      else if (p == 27) { wsrc = w1;                  stride = 128; }
      if (wsrc) {
        for (int e = 0; e < EN; e++) {
          const float* src = wsrc + e * stride + c0;
          const float4 v0 = *(const float4*)(src);
          const float4 v1 = *(const float4*)(src + 4);
          const float4 v2 = *(const float4*)(src + 8);
          const float4 v3 = *(const float4*)(src + 12);
          acc[0]  += yv[e] * v0.x; acc[1]  += yv[e] * v0.y;
          acc[2]  += yv[e] * v0.z; acc[3]  += yv[e] * v0.w;
          acc[4]  += yv[e] * v1.x; acc[5]  += yv[e] * v1.y;
          acc[6]  += yv[e] * v1.z; acc[7]  += yv[e] * v1.w;
          acc[8]  += yv[e] * v2.x; acc[9]  += yv[e] * v2.y;
          acc[10] += yv[e] * v2.z; acc[11] += yv[e] * v2.w;
          acc[12] += yv[e] * v3.x; acc[13] += yv[e] * v3.y;
          acc[14] += yv[e] * v3.z; acc[15] += yv[e] * v3.w;
        }
      }
#pragma unroll
      for (int m = 0; m < 16; m++) wbl[nl][p * 128 + c0 + m] = f2bf(acc[m]);
    }
    __syncthreads();

    // wave handles 32 pairs; 4 waves per node, 2 nodes per block
    const int bnode = node0 + nw;
    const int pair0 = bnode * 128 + wn * 32 + col;

    float xr[16];
    load_xr(x, pair0, q, xr);

    f32x16 acc = {0.f, 0.f, 0.f, 0.f, 0.f, 0.f, 0.f, 0.f,
                  0.f, 0.f, 0.f, 0.f, 0.f, 0.f, 0.f, 0.f};
    run_chunks(std::make_integer_sequence<int, NCHUNK>{}, sfl, sgl, xr, acc);

    // epilogue: out[pair] = sum_p D[p][pair] * WB[p][c], reduce over the
    // two lane-halves.  D layout (32x32, m74/m101-verified):
    // col = lane&31 = pair, row = (reg&3) + 8*(reg>>2) + 4*q = path.
    // Rows 28..31 (q=1, reg 12..15) have zero D and zero wbl -> branchless.
    const int cc = wn * 32 + col;              // channel = pair0 % 128
    float p0 = 0.f;
#pragma unroll
    for (int r = 0; r < 16; r++) {
      const int row = (r & 3) + 8 * (r >> 2) + 4 * q;
      p0 += acc[r] * bf2f(wbl[nw][row * 128 + cc]);
    }
    p0 += __shfl_xor(p0, 32);
    if (q == 0) out[pair0] = p0;

    // guard: wbl overwritten by next iteration's WB phase
    __syncthreads();
  }
}

// ------------------------------------------------------------------
extern "C" void kernel_launch(void* const* d_in, const int* in_sizes, int n_in,
                              void* d_out, int out_size, void* d_ws, size_t ws_size,
                              hipStream_t stream) {
  const float* x  = (const float*)d_in[0];
  const float* y  = (const float*)d_in[1];
  const float* U3 = (const float*)d_in[2];
  const float* U2 = (const float*)d_in[3];
  const float* U1 = (const float*)d_in[4];
  const float* w3 = (const float*)d_in[5];
  const float* w2 = (const float*)d_in[6];
  const float* w1 = (const float*)d_in[7];
  u16*   Sfrag16 = (u16*)d_ws;
  float* out     = (float*)d_out;

  hipLaunchKernelGGL(prep_kernel, dim3(PREP_THREADS / 256), dim3(256), 0, stream,
                     U3, U2, U1, Sfrag16);
  hipLaunchKernelGGL(main_kernel, dim3(GRID), dim3(512), 0, stream,
                     x, y, w3, w2, w1, (const uint4*)d_ws, out);
}

// Round 7
// 183.936 us; speedup vs baseline: 1.7565x; 1.7565x over previous
//
#include <hip/hip_runtime.h>
#include <utility>

using u16 = unsigned short;
using u32 = unsigned int;

typedef float  f32x2   __attribute__((ext_vector_type(2)));
typedef float  f32x4   __attribute__((ext_vector_type(4)));
typedef float  f32x16  __attribute__((ext_vector_type(16)));
typedef __bf16 bf16x8  __attribute__((ext_vector_type(8)));

#define DI __device__ __forceinline__

// ------------------------------------------------------------------
// Monomial basis under the +8 rotation group (for 32x32x16 MFMA).
// Monomials over x[0..15]: cubic (816), quadratic (136), linear (16).
// Group action: rotation by +8q mod 16 (q=0..1).  Cubic orbits all size
// 2 (parity: 3*8=24 != 0 mod 16) -> 408 reps; quad: 8 fixed orbits
// {a,a+8} + 64 size-2 -> 72 reps (8 dup slots stay null); linear -> 8
// reps.  408+72+8 = 488 = 61 chunks * 8 exactly (no padding).
// Chunk t-homogeneity: 408/8=51 cubic chunks (0..50), 72/8=9 quad
// (51..59), 8/8=1 linear (60) -> every chunk has a single t, so
// feature-PAIRS pack cleanly into f32x2 ops (v_pk_mul_f32).
// Feature slot f = chunk*16 + q*8 + j  <->  rep r = chunk*8 + j,
// monomial = rot_{8q}(rep[r]).  Lane half q = lane>>5 holds x rotated by
// 8q at the address level, so all lanes run identical compile-time code.
// ------------------------------------------------------------------
struct RepT { unsigned char a, b, c, t; };   // t: 3=cubic 2=quad 1=linear 0=null
struct Tables8 {
  RepT rep[488];        // compile-time rep list for feature templates
  RepT slotmono[976];   // per feature-slot: SORTED monomial (prep gather); t=0 if dup
  int n3, n2, n1;
};

constexpr int csort3key(int w, int x, int i) {
  int a = w, b = x, c = i, t = 0;
  if (a > b) { t = a; a = b; b = t; }
  if (b > c) { t = b; b = c; c = t; }
  if (a > b) { t = a; a = b; b = t; }
  return (a << 8) | (b << 4) | c;
}
constexpr int csort2key(int a, int b) { return a <= b ? ((a << 4) | b) : ((b << 4) | a); }

constexpr Tables8 build_tables8() {
  Tables8 T = {};
  bool used3[4096] = {};
  bool used2[256] = {};
  int nr = 0;
  // cubic multisets a<=b<=c, canonical = lex-min of {self, +8 rotation}
  for (int a = 0; a < 16; a++) for (int b = a; b < 16; b++) for (int c = b; c < 16; c++) {
    const int key  = (a << 8) | (b << 4) | c;
    const int rkey = csort3key((a + 8) & 15, (b + 8) & 15, (c + 8) & 15);
    if (rkey < key) continue;                 // partner is the canonical one
    for (int q = 0; q < 2; q++) {
      const int kk = q ? rkey : key;
      if (!used3[kk]) {
        used3[kk] = true;
        const int f = (nr >> 3) * 16 + q * 8 + (nr & 7);
        T.slotmono[f].a = (unsigned char)(kk >> 8);
        T.slotmono[f].b = (unsigned char)((kk >> 4) & 15);
        T.slotmono[f].c = (unsigned char)(kk & 15);
        T.slotmono[f].t = 3;
      }
    }
    T.rep[nr].a = (unsigned char)a; T.rep[nr].b = (unsigned char)b;
    T.rep[nr].c = (unsigned char)c; T.rep[nr].t = 3; nr++;
  }
  T.n3 = nr;
  // quadratic multisets a<=b
  for (int a = 0; a < 16; a++) for (int b = a; b < 16; b++) {
    const int key  = (a << 4) | b;
    const int rkey = csort2key((a + 8) & 15, (b + 8) & 15);
    if (rkey < key) continue;
    for (int q = 0; q < 2; q++) {
      const int kk = q ? rkey : key;
      if (!used2[kk]) {                      // fixed orbits: q=1 slot stays null
        used2[kk] = true;
        const int f = (nr >> 3) * 16 + q * 8 + (nr & 7);
        T.slotmono[f].a = (unsigned char)(kk >> 4);
        T.slotmono[f].b = (unsigned char)(kk & 15);
        T.slotmono[f].c = 0;
        T.slotmono[f].t = 2;
      }
    }
    T.rep[nr].a = (unsigned char)a; T.rep[nr].b = (unsigned char)b;
    T.rep[nr].c = 0; T.rep[nr].t = 2; nr++;
  }
  T.n2 = nr;
  // linear: reps 0..7, orbit {a, a+8}
  for (int a = 0; a < 8; a++) {
    for (int q = 0; q < 2; q++) {
      const int f = (nr >> 3) * 16 + q * 8 + (nr & 7);
      T.slotmono[f].a = (unsigned char)((a + 8 * q) & 15);
      T.slotmono[f].b = 0; T.slotmono[f].c = 0; T.slotmono[f].t = 1;
    }
    T.rep[nr].a = (unsigned char)a; T.rep[nr].b = 0; T.rep[nr].c = 0;
    T.rep[nr].t = 1; nr++;
  }
  T.n1 = nr;
  return T;
}

constexpr Tables8 TT8 = build_tables8();
static_assert(TT8.n3 == 408, "cubic rep count");
static_assert(TT8.n2 == 480, "quad rep count");
static_assert(TT8.n1 == 488, "linear rep count");   // 61 chunks * 8, exact

__device__ const Tables8 g_T8 = build_tables8();   // runtime copy for prep kernel

// dims
#define BN 5888
#define CN 128
#define EN 10
#define NCHUNK 61          // 488 reps / 8; K = 976

DI u16 f2bf(float f) { union { __bf16 h; u16 s; } u; u.h = (__bf16)f; return u.s; }
DI float bf2f(u16 v) { union { u32 u; float f; } w; w.u = ((u32)v) << 16; return w.f; }

// ------------------------------------------------------------------
// prep kernel: ONE dispatch, no memset, no atomics.  One thread per
// packed-fragment u16: gathers its monomial's <=6 distinct U-index
// permutations, sums, converts to bf16, writes coalesced.
// Fragment layout (matches main's staging copy exactly):
// uint4 idx = chunk*64 + l; lane l: path = l&31, q = l>>5; u16 j in
// [0,8): feature slot = chunk*16 + q*8 + j.  Paths 28..31 are zero.
// ------------------------------------------------------------------
#define PREP_THREADS (NCHUNK * 64 * 8)     // 31232 u16 = 61 KB

__global__ void prep_kernel(const float* __restrict__ U3, const float* __restrict__ U2,
                            const float* __restrict__ U1, u16* __restrict__ Sfrag16) {
  const int tid = blockIdx.x * 256 + threadIdx.x;
  if (tid >= PREP_THREADS) return;
  const int j = tid & 7, l = (tid >> 3) & 63, chunk = tid >> 9;
  const int path = l & 31, q = l >> 5;
  const RepT m = g_T8.slotmono[chunk * 16 + q * 8 + j];
  float v = 0.f;
  if (m.t == 3 && path < 23) {
    const int a = m.a, b = m.b, d = m.c;
    v = U3[((a * 16 + b) * 16 + d) * 23 + path];
    if (a == b && b == d) {
      // single distinct permutation
    } else if (a == b) {            // (a,a,d): +ada, +daa
      v += U3[((a * 16 + d) * 16 + a) * 23 + path]
         + U3[((d * 16 + a) * 16 + a) * 23 + path];
    } else if (b == d) {            // (a,b,b): +bab, +bba
      v += U3[((b * 16 + a) * 16 + b) * 23 + path]
         + U3[((b * 16 + b) * 16 + a) * 23 + path];
    } else {                        // all distinct: 6 perms
      v += U3[((a * 16 + d) * 16 + b) * 23 + path]
         + U3[((b * 16 + a) * 16 + d) * 23 + path]
         + U3[((b * 16 + d) * 16 + a) * 23 + path]
         + U3[((d * 16 + a) * 16 + b) * 23 + path]
         + U3[((d * 16 + b) * 16 + a) * 23 + path];
    }
  } else if (m.t == 2 && path >= 23 && path < 27) {
    const int k = path - 23, a = m.a, b = m.b;
    v = U2[(a * 16 + b) * 4 + k];
    if (a != b) v += U2[(b * 16 + a) * 4 + k];
  } else if (m.t == 1 && path == 27) {
    v = U1[m.a];
  }
  Sfrag16[tid] = f2bf(v);
}

// ------------------------------------------------------------------
// main kernel (32x32x16 MFMA).  Journal of hard-won constraints:
//  - NEVER demand occupancy beyond the VGPR budget via launch_bounds
//    min-waves (round 0: clamp to 32 VGPR -> 430 MB scratch traffic).
//  - NO sched_barrier (prior round 10: 8x regression).
//  - w-reads block-coalesced once (prior round 5: 990 MB L2 fetch).
//  - Round 2: K-splitting across waves doubles per-wave fixed costs.
//  - Round 4: global A-path -> VGPR 76 (>64 halves wave cap) = 120 us.
//  - Round 5: hybrid A + persistent loop -> LICM hoisted the loop-
//    invariant global A-loads, spilled (FETCH 388 MB, WRITE 218 MB,
//    250 us).  NEVER keep a big loop-invariant global-load set inside
//    a persistent loop.  A-path stays ds_read; r3 structure is the
//    proven optimum (103 us, VGPR 64, 2 blocks/CU).
// THIS ROUND (r3 + intra-wave work reduction):
//  1. f32x2-packed feature math -> v_pk_mul_f32 (VOP3P, 2 muls/instr).
//     Chunks are t-homogeneous so all 4 feature-pairs pack cleanly.
//     Halves the dominant VALU phase (54 us -> ~38).
//  2. Dual accumulators (even->acc0, odd->acc1): breaks the 61-MFMA
//     serial chain, lets MFMA issue back-to-back and overlap VALU.
//     +16 VGPR (~80-96 total), within (512,4)'s 128 budget; LDS still
//     the occupancy limiter so no occupancy change.
// ------------------------------------------------------------------

// packed feature pair: features R0 and R0+1 (same t by chunk homogeneity)
template<int R0>
DI f32x2 feat2(const float* xr) {
  constexpr RepT ra = TT8.rep[R0];
  constexpr RepT rb = TT8.rep[R0 + 1];
  static_assert(ra.t == rb.t, "chunk not t-homogeneous");
  f32x2 v = {xr[ra.a], xr[rb.a]};
  if constexpr (ra.t >= 2) { const f32x2 w = {xr[ra.b], xr[rb.b]}; v *= w; }
  if constexpr (ra.t >= 3) { const f32x2 w = {xr[ra.c], xr[rb.c]}; v *= w; }
  return v;
}

template<int C>
DI bf16x8 make_B(const float* xr) {
  const f32x2 p0 = feat2<C * 8 + 0>(xr);
  const f32x2 p1 = feat2<C * 8 + 2>(xr);
  const f32x2 p2 = feat2<C * 8 + 4>(xr);
  const f32x2 p3 = feat2<C * 8 + 6>(xr);
  bf16x8 r;
  r[0] = (__bf16)p0.x; r[1] = (__bf16)p0.y;
  r[2] = (__bf16)p1.x; r[3] = (__bf16)p1.y;
  r[4] = (__bf16)p2.x; r[5] = (__bf16)p2.y;
  r[6] = (__bf16)p3.x; r[7] = (__bf16)p3.y;
  return r;
}

// A: 32 paths x 16 K fragment from LDS (one ds_read_b128); B: 8
// features of this pair.  B built before the A-load to keep A's live
// range ds_read -> MFMA.
template<int C>
DI void chunk_step(const uint4* sfl, const float* xr, f32x16& acc) {
  const bf16x8 B = make_B<C>(xr);
  const bf16x8 A = *reinterpret_cast<const bf16x8*>(sfl + C * 64);
  acc = __builtin_amdgcn_mfma_f32_32x32x16_bf16(A, B, acc, 0, 0, 0);
}

template<int... Cs>
DI void run_chunks(std::integer_sequence<int, Cs...>, const uint4* sfl,
                   const float* xr, f32x16& acc0, f32x16& acc1) {
  (chunk_step<Cs>(sfl, xr, (Cs & 1) ? acc1 : acc0), ...);
}

// xr[v] = x[pair][(v + 8q) & 15] via float4-group rotation (2 groups = 8)
DI void load_xr(const float* __restrict__ x, int pair, int q, float* xr) {
  const float* base = x + pair * 16;
#pragma unroll
  for (int u = 0; u < 4; u++) {
    const int g = (u + 2 * q) & 3;
    const float4 v = *(const float4*)(base + g * 4);
    xr[u * 4 + 0] = v.x;
    xr[u * 4 + 1] = v.y;
    xr[u * 4 + 2] = v.z;
    xr[u * 4 + 3] = v.w;
  }
}

// 512-thread blocks: 8 waves = 2 nodes (4 waves x 32 pairs each).
// LDS = 61 KB sfrag (shared) + 2*8 KB wbl = 77 KB -> 2 blocks/CU.
// launch_bounds (512,4): 4 waves/EU is exactly the LDS-bound occupancy;
// grants a 128-VGPR budget (expected use ~80-96, no spill).
__global__ __launch_bounds__(512, 4) void main_kernel(
    const float* __restrict__ x, const float* __restrict__ y,
    const float* __restrict__ w3, const float* __restrict__ w2, const float* __restrict__ w1,
    const uint4* __restrict__ Sfrag, float* __restrict__ out)
{
  __shared__ uint4 sfrag[NCHUNK * 64];         // 62464 B: S in A-frag order
  __shared__ u16  wbl[2][32 * 128];            // 16384 B: WB[path][c] bf16, per node
  const int tid = threadIdx.x;
  const int node0 = blockIdx.x * 2;

  // stage S: straight uint4 copy (prep already packed bf16 fragments)
  for (int idx = tid; idx < NCHUNK * 64; idx += 512) sfrag[idx] = Sfrag[idx];

  // per-node WB = y[b] @ concat(w3,w2,w1).  256 threads/node:
  // tl = tid&255 -> p = tl>>3 (32 paths), c-16-seg = (tl&7)*16.
  // Rows 28..31: wsrc null -> zeros written (branchless epilogue).
  const int nl = tid >> 8;                     // node-local index 0/1
  const int bnode = node0 + nl;
  {
    const int tl = tid & 255;
    const int p  = tl >> 3;
    const int c0 = (tl & 7) * 16;
    float yv[EN];
#pragma unroll
    for (int e = 0; e < EN; e++) yv[e] = y[bnode * EN + e];
    float acc[16];
#pragma unroll
    for (int m = 0; m < 16; m++) acc[m] = 0.f;
    const float* wsrc = nullptr; int stride = 0;
    if (p < 23)       { wsrc = w3 + p * 128;        stride = 23 * 128; }
    else if (p < 27)  { wsrc = w2 + (p - 23) * 128; stride = 4 * 128; }
    else if (p == 27) { wsrc = w1;                  stride = 128; }
    if (wsrc) {
      for (int e = 0; e < EN; e++) {
        const float* src = wsrc + e * stride + c0;
        const float4 v0 = *(const float4*)(src);
        const float4 v1 = *(const float4*)(src + 4);
        const float4 v2 = *(const float4*)(src + 8);
        const float4 v3 = *(const float4*)(src + 12);
        acc[0]  += yv[e] * v0.x; acc[1]  += yv[e] * v0.y;
        acc[2]  += yv[e] * v0.z; acc[3]  += yv[e] * v0.w;
        acc[4]  += yv[e] * v1.x; acc[5]  += yv[e] * v1.y;
        acc[6]  += yv[e] * v1.z; acc[7]  += yv[e] * v1.w;
        acc[8]  += yv[e] * v2.x; acc[9]  += yv[e] * v2.y;
        acc[10] += yv[e] * v2.z; acc[11] += yv[e] * v2.w;
        acc[12] += yv[e] * v3.x; acc[13] += yv[e] * v3.y;
        acc[14] += yv[e] * v3.z; acc[15] += yv[e] * v3.w;
      }
    }
#pragma unroll
    for (int m = 0; m < 16; m++) wbl[nl][p * 128 + c0 + m] = f2bf(acc[m]);
  }
  __syncthreads();

  // wave handles 32 pairs; 4 waves per node, 2 nodes per block
  const int w = tid >> 6, wn = w & 3, nw = w >> 2;
  const int lane = tid & 63, col = lane & 31, q = lane >> 5;
  const int mnode = node0 + nw;
  const int pair0 = mnode * 128 + wn * 32 + col;

  float xr[16];
  load_xr(x, pair0, q, xr);

  const uint4* sfl = sfrag + lane;
  f32x16 acc0 = {0.f, 0.f, 0.f, 0.f, 0.f, 0.f, 0.f, 0.f,
                 0.f, 0.f, 0.f, 0.f, 0.f, 0.f, 0.f, 0.f};
  f32x16 acc1 = acc0;
  run_chunks(std::make_integer_sequence<int, NCHUNK>{}, sfl, xr, acc0, acc1);
  const f32x16 acc = acc0 + acc1;

  // epilogue: out[pair] = sum_p D[p][pair] * WB[p][c], reduce over the
  // two lane-halves.  D layout (32x32, m74/m101-verified):
  // col = lane&31 = pair, row = (reg&3) + 8*(reg>>2) + 4*q = path.
  // Rows 28..31 (q=1, reg 12..15) have zero D (zero A-rows) and zero
  // wbl -> branchless.
  const int cc = wn * 32 + col;              // channel = pair0 % 128
  float p0 = 0.f;
#pragma unroll
  for (int r = 0; r < 16; r++) {
    const int row = (r & 3) + 8 * (r >> 2) + 4 * q;
    p0 += acc[r] * bf2f(wbl[nw][row * 128 + cc]);
  }
  p0 += __shfl_xor(p0, 32);
  if (q == 0) out[pair0] = p0;
}

// ------------------------------------------------------------------
extern "C" void kernel_launch(void* const* d_in, const int* in_sizes, int n_in,
                              void* d_out, int out_size, void* d_ws, size_t ws_size,
                              hipStream_t stream) {
  const float* x  = (const float*)d_in[0];
  const float* y  = (const float*)d_in[1];
  const float* U3 = (const float*)d_in[2];
  const float* U2 = (const float*)d_in[3];
  const float* U1 = (const float*)d_in[4];
  const float* w3 = (const float*)d_in[5];
  const float* w2 = (const float*)d_in[6];
  const float* w1 = (const float*)d_in[7];
  u16*   Sfrag16 = (u16*)d_ws;
  float* out     = (float*)d_out;

  hipLaunchKernelGGL(prep_kernel, dim3(PREP_THREADS / 256), dim3(256), 0, stream,
                     U3, U2, U1, Sfrag16);
  hipLaunchKernelGGL(main_kernel, dim3(BN / 2), dim3(512), 0, stream,
                     x, y, w3, w2, w1, (const uint4*)d_ws, out);
}

// Round 8
// 180.445 us; speedup vs baseline: 1.7905x; 1.0193x over previous
//
#include <hip/hip_runtime.h>
#include <utility>

using u16 = unsigned short;
using u32 = unsigned int;

typedef float  f32x2   __attribute__((ext_vector_type(2)));
typedef float  f32x4   __attribute__((ext_vector_type(4)));
typedef float  f32x16  __attribute__((ext_vector_type(16)));
typedef __bf16 bf16x8  __attribute__((ext_vector_type(8)));

#define DI __device__ __forceinline__

// ------------------------------------------------------------------
// Monomial basis under the +8 rotation group (for 32x32x16 MFMA).
// Monomials over x[0..15]: cubic (816), quadratic (136), linear (16).
// Group action: rotation by +8q mod 16 (q=0..1).  Cubic orbits all size
// 2 (parity: 3*8=24 != 0 mod 16) -> 408 reps; quad: 8 fixed orbits
// {a,a+8} + 64 size-2 -> 72 reps (8 dup slots stay null); linear -> 8
// reps.  408+72+8 = 488 = 61 chunks * 8 exactly (no padding).
// Chunk t-homogeneity: 51 cubic chunks (0..50), 9 quad (51..59), 1
// linear (60) -> every chunk has a single t, so feature-PAIRS pack
// cleanly into f32x2 ops (v_pk_mul_f32).
// Feature slot f = chunk*16 + q*8 + j  <->  rep r = chunk*8 + j,
// monomial = rot_{8q}(rep[r]).  Lane half q = lane>>5 holds x rotated by
// 8q at the address level, so all lanes run identical compile-time code.
// ------------------------------------------------------------------
struct RepT { unsigned char a, b, c, t; };   // t: 3=cubic 2=quad 1=linear 0=null
struct Tables8 {
  RepT rep[488];        // compile-time rep list for feature templates
  RepT slotmono[976];   // per feature-slot: SORTED monomial (prep gather); t=0 if dup
  int n3, n2, n1;
};

constexpr int csort3key(int w, int x, int i) {
  int a = w, b = x, c = i, t = 0;
  if (a > b) { t = a; a = b; b = t; }
  if (b > c) { t = b; b = c; c = t; }
  if (a > b) { t = a; a = b; b = t; }
  return (a << 8) | (b << 4) | c;
}
constexpr int csort2key(int a, int b) { return a <= b ? ((a << 4) | b) : ((b << 4) | a); }

constexpr Tables8 build_tables8() {
  Tables8 T = {};
  bool used3[4096] = {};
  bool used2[256] = {};
  int nr = 0;
  // cubic multisets a<=b<=c, canonical = lex-min of {self, +8 rotation}
  for (int a = 0; a < 16; a++) for (int b = a; b < 16; b++) for (int c = b; c < 16; c++) {
    const int key  = (a << 8) | (b << 4) | c;
    const int rkey = csort3key((a + 8) & 15, (b + 8) & 15, (c + 8) & 15);
    if (rkey < key) continue;                 // partner is the canonical one
    for (int q = 0; q < 2; q++) {
      const int kk = q ? rkey : key;
      if (!used3[kk]) {
        used3[kk] = true;
        const int f = (nr >> 3) * 16 + q * 8 + (nr & 7);
        T.slotmono[f].a = (unsigned char)(kk >> 8);
        T.slotmono[f].b = (unsigned char)((kk >> 4) & 15);
        T.slotmono[f].c = (unsigned char)(kk & 15);
        T.slotmono[f].t = 3;
      }
    }
    T.rep[nr].a = (unsigned char)a; T.rep[nr].b = (unsigned char)b;
    T.rep[nr].c = (unsigned char)c; T.rep[nr].t = 3; nr++;
  }
  T.n3 = nr;
  // quadratic multisets a<=b
  for (int a = 0; a < 16; a++) for (int b = a; b < 16; b++) {
    const int key  = (a << 4) | b;
    const int rkey = csort2key((a + 8) & 15, (b + 8) & 15);
    if (rkey < key) continue;
    for (int q = 0; q < 2; q++) {
      const int kk = q ? rkey : key;
      if (!used2[kk]) {                      // fixed orbits: q=1 slot stays null
        used2[kk] = true;
        const int f = (nr >> 3) * 16 + q * 8 + (nr & 7);
        T.slotmono[f].a = (unsigned char)(kk >> 4);
        T.slotmono[f].b = (unsigned char)(kk & 15);
        T.slotmono[f].c = 0;
        T.slotmono[f].t = 2;
      }
    }
    T.rep[nr].a = (unsigned char)a; T.rep[nr].b = (unsigned char)b;
    T.rep[nr].c = 0; T.rep[nr].t = 2; nr++;
  }
  T.n2 = nr;
  // linear: reps 0..7, orbit {a, a+8}
  for (int a = 0; a < 8; a++) {
    for (int q = 0; q < 2; q++) {
      const int f = (nr >> 3) * 16 + q * 8 + (nr & 7);
      T.slotmono[f].a = (unsigned char)((a + 8 * q) & 15);
      T.slotmono[f].b = 0; T.slotmono[f].c = 0; T.slotmono[f].t = 1;
    }
    T.rep[nr].a = (unsigned char)a; T.rep[nr].b = 0; T.rep[nr].c = 0;
    T.rep[nr].t = 1; nr++;
  }
  T.n1 = nr;
  return T;
}

constexpr Tables8 TT8 = build_tables8();
static_assert(TT8.n3 == 408, "cubic rep count");
static_assert(TT8.n2 == 480, "quad rep count");
static_assert(TT8.n1 == 488, "linear rep count");   // 61 chunks * 8, exact

__device__ const Tables8 g_T8 = build_tables8();   // runtime copy for prep kernel

// dims
#define BN 5888
#define CN 128
#define EN 10
#define NCHUNK 61          // 488 reps / 8; K = 976

DI u16 f2bf(float f) { union { __bf16 h; u16 s; } u; u.h = (__bf16)f; return u.s; }
DI float bf2f(u16 v) { union { u32 u; float f; } w; w.u = ((u32)v) << 16; return w.f; }

// ------------------------------------------------------------------
// prep kernel: ONE dispatch, no memset, no atomics.  One thread per
// packed-fragment u16: gathers its monomial's <=6 distinct U-index
// permutations, sums, converts to bf16, writes coalesced.
// Fragment layout (matches main's staging copy exactly):
// uint4 idx = chunk*64 + l; lane l: path = l&31, q = l>>5; u16 j in
// [0,8): feature slot = chunk*16 + q*8 + j.  Paths 28..31 are zero.
// ------------------------------------------------------------------
#define PREP_THREADS (NCHUNK * 64 * 8)     // 31232 u16 = 61 KB

__global__ void prep_kernel(const float* __restrict__ U3, const float* __restrict__ U2,
                            const float* __restrict__ U1, u16* __restrict__ Sfrag16) {
  const int tid = blockIdx.x * 256 + threadIdx.x;
  if (tid >= PREP_THREADS) return;
  const int j = tid & 7, l = (tid >> 3) & 63, chunk = tid >> 9;
  const int path = l & 31, q = l >> 5;
  const RepT m = g_T8.slotmono[chunk * 16 + q * 8 + j];
  float v = 0.f;
  if (m.t == 3 && path < 23) {
    const int a = m.a, b = m.b, d = m.c;
    v = U3[((a * 16 + b) * 16 + d) * 23 + path];
    if (a == b && b == d) {
      // single distinct permutation
    } else if (a == b) {            // (a,a,d): +ada, +daa
      v += U3[((a * 16 + d) * 16 + a) * 23 + path]
         + U3[((d * 16 + a) * 16 + a) * 23 + path];
    } else if (b == d) {            // (a,b,b): +bab, +bba
      v += U3[((b * 16 + a) * 16 + b) * 23 + path]
         + U3[((b * 16 + b) * 16 + a) * 23 + path];
    } else {                        // all distinct: 6 perms
      v += U3[((a * 16 + d) * 16 + b) * 23 + path]
         + U3[((b * 16 + a) * 16 + d) * 23 + path]
         + U3[((b * 16 + d) * 16 + a) * 23 + path]
         + U3[((d * 16 + a) * 16 + b) * 23 + path]
         + U3[((d * 16 + b) * 16 + a) * 23 + path];
    }
  } else if (m.t == 2 && path >= 23 && path < 27) {
    const int k = path - 23, a = m.a, b = m.b;
    v = U2[(a * 16 + b) * 4 + k];
    if (a != b) v += U2[(b * 16 + a) * 4 + k];
  } else if (m.t == 1 && path == 27) {
    v = U1[m.a];
  }
  Sfrag16[tid] = f2bf(v);
}

// ------------------------------------------------------------------
// main kernel (32x32x16 MFMA).  Journal of hard-won constraints:
//  - NEVER demand occupancy beyond the VGPR budget via launch_bounds
//    min-waves (round 0: clamp to 32 VGPR -> 430 MB scratch traffic).
//  - NO sched_barrier (prior round 10: 8x regression).
//  - w-reads block-coalesced once (prior round 5: 990 MB L2 fetch).
//  - Round 2: K-splitting across waves doubles per-wave fixed costs.
//  - Round 4: global A-path -> VGPR 76 (>64 halves wave cap) = 120 us.
//  - Round 5: persistent loop + loop-invariant global A-loads -> LICM
//    spill (WRITE 218 MB, 250 us).  A-path stays ds_read.
//  - Round 6: f32x2-packed features WORKED (VALU 54 -> 43 us) but dual
//    f32x16 accumulators overflowed the unified VGPR+AGPR envelope ->
//    25 MB scratch (WRITE 28 MB), 113 us.  Dual-acc is pointless anyway:
//    at 4 waves/SIMD, TLP hides the MFMA dep-chain.
// THIS ROUND: r3 structure + packed features, SINGLE accumulator.
// ------------------------------------------------------------------

// packed feature pair: features R0 and R0+1 (same t by chunk homogeneity)
template<int R0>
DI f32x2 feat2(const float* xr) {
  constexpr RepT ra = TT8.rep[R0];
  constexpr RepT rb = TT8.rep[R0 + 1];
  static_assert(ra.t == rb.t, "chunk not t-homogeneous");
  f32x2 v = {xr[ra.a], xr[rb.a]};
  if constexpr (ra.t >= 2) { const f32x2 w = {xr[ra.b], xr[rb.b]}; v *= w; }
  if constexpr (ra.t >= 3) { const f32x2 w = {xr[ra.c], xr[rb.c]}; v *= w; }
  return v;
}

template<int C>
DI bf16x8 make_B(const float* xr) {
  const f32x2 p0 = feat2<C * 8 + 0>(xr);
  const f32x2 p1 = feat2<C * 8 + 2>(xr);
  const f32x2 p2 = feat2<C * 8 + 4>(xr);
  const f32x2 p3 = feat2<C * 8 + 6>(xr);
  bf16x8 r;
  r[0] = (__bf16)p0.x; r[1] = (__bf16)p0.y;
  r[2] = (__bf16)p1.x; r[3] = (__bf16)p1.y;
  r[4] = (__bf16)p2.x; r[5] = (__bf16)p2.y;
  r[6] = (__bf16)p3.x; r[7] = (__bf16)p3.y;
  return r;
}

// A: 32 paths x 16 K fragment from LDS (one ds_read_b128); B: 8
// features of this pair.  B built before the A-load to keep A's live
// range ds_read -> MFMA.
template<int C>
DI void chunk_step(const uint4* sfl, const float* xr, f32x16& acc) {
  const bf16x8 B = make_B<C>(xr);
  const bf16x8 A = *reinterpret_cast<const bf16x8*>(sfl + C * 64);
  acc = __builtin_amdgcn_mfma_f32_32x32x16_bf16(A, B, acc, 0, 0, 0);
}

template<int... Cs>
DI void run_chunks(std::integer_sequence<int, Cs...>, const uint4* sfl,
                   const float* xr, f32x16& acc) {
  (chunk_step<Cs>(sfl, xr, acc), ...);
}

// xr[v] = x[pair][(v + 8q) & 15] via float4-group rotation (2 groups = 8)
DI void load_xr(const float* __restrict__ x, int pair, int q, float* xr) {
  const float* base = x + pair * 16;
#pragma unroll
  for (int u = 0; u < 4; u++) {
    const int g = (u + 2 * q) & 3;
    const float4 v = *(const float4*)(base + g * 4);
    xr[u * 4 + 0] = v.x;
    xr[u * 4 + 1] = v.y;
    xr[u * 4 + 2] = v.z;
    xr[u * 4 + 3] = v.w;
  }
}

// 512-thread blocks: 8 waves = 2 nodes (4 waves x 32 pairs each).
// LDS = 61 KB sfrag (shared) + 2*8 KB wbl = 77 KB -> 2 blocks/CU.
// launch_bounds (512,4): 4 waves/EU is exactly the LDS-bound occupancy;
// grants a 128-VGPR budget (r3-proven spill-free at VGPR 64 + 16 AGPR).
__global__ __launch_bounds__(512, 4) void main_kernel(
    const float* __restrict__ x, const float* __restrict__ y,
    const float* __restrict__ w3, const float* __restrict__ w2, const float* __restrict__ w1,
    const uint4* __restrict__ Sfrag, float* __restrict__ out)
{
  __shared__ uint4 sfrag[NCHUNK * 64];         // 62464 B: S in A-frag order
  __shared__ u16  wbl[2][32 * 128];            // 16384 B: WB[path][c] bf16, per node
  const int tid = threadIdx.x;
  const int node0 = blockIdx.x * 2;

  // stage S: straight uint4 copy (prep already packed bf16 fragments)
  for (int idx = tid; idx < NCHUNK * 64; idx += 512) sfrag[idx] = Sfrag[idx];

  // per-node WB = y[b] @ concat(w3,w2,w1).  256 threads/node:
  // tl = tid&255 -> p = tl>>3 (32 paths), c-16-seg = (tl&7)*16.
  // Rows 28..31: wsrc null -> zeros written (branchless epilogue).
  const int nl = tid >> 8;                     // node-local index 0/1
  const int bnode = node0 + nl;
  {
    const int tl = tid & 255;
    const int p  = tl >> 3;
    const int c0 = (tl & 7) * 16;
    float yv[EN];
#pragma unroll
    for (int e = 0; e < EN; e++) yv[e] = y[bnode * EN + e];
    float acc[16];
#pragma unroll
    for (int m = 0; m < 16; m++) acc[m] = 0.f;
    const float* wsrc = nullptr; int stride = 0;
    if (p < 23)       { wsrc = w3 + p * 128;        stride = 23 * 128; }
    else if (p < 27)  { wsrc = w2 + (p - 23) * 128; stride = 4 * 128; }
    else if (p == 27) { wsrc = w1;                  stride = 128; }
    if (wsrc) {
      for (int e = 0; e < EN; e++) {
        const float* src = wsrc + e * stride + c0;
        const float4 v0 = *(const float4*)(src);
        const float4 v1 = *(const float4*)(src + 4);
        const float4 v2 = *(const float4*)(src + 8);
        const float4 v3 = *(const float4*)(src + 12);
        acc[0]  += yv[e] * v0.x; acc[1]  += yv[e] * v0.y;
        acc[2]  += yv[e] * v0.z; acc[3]  += yv[e] * v0.w;
        acc[4]  += yv[e] * v1.x; acc[5]  += yv[e] * v1.y;
        acc[6]  += yv[e] * v1.z; acc[7]  += yv[e] * v1.w;
        acc[8]  += yv[e] * v2.x; acc[9]  += yv[e] * v2.y;
        acc[10] += yv[e] * v2.z; acc[11] += yv[e] * v2.w;
        acc[12] += yv[e] * v3.x; acc[13] += yv[e] * v3.y;
        acc[14] += yv[e] * v3.z; acc[15] += yv[e] * v3.w;
      }
    }
#pragma unroll
    for (int m = 0; m < 16; m++) wbl[nl][p * 128 + c0 + m] = f2bf(acc[m]);
  }
  __syncthreads();

  // wave handles 32 pairs; 4 waves per node, 2 nodes per block
  const int w = tid >> 6, wn = w & 3, nw = w >> 2;
  const int lane = tid & 63, col = lane & 31, q = lane >> 5;
  const int mnode = node0 + nw;
  const int pair0 = mnode * 128 + wn * 32 + col;

  float xr[16];
  load_xr(x, pair0, q, xr);

  const uint4* sfl = sfrag + lane;
  f32x16 acc = {0.f, 0.f, 0.f, 0.f, 0.f, 0.f, 0.f, 0.f,
                0.f, 0.f, 0.f, 0.f, 0.f, 0.f, 0.f, 0.f};
  run_chunks(std::make_integer_sequence<int, NCHUNK>{}, sfl, xr, acc);

  // epilogue: out[pair] = sum_p D[p][pair] * WB[p][c], reduce over the
  // two lane-halves.  D layout (32x32, m74/m101-verified):
  // col = lane&31 = pair, row = (reg&3) + 8*(reg>>2) + 4*q = path.
  // Rows 28..31 (q=1, reg 12..15) have zero D (zero A-rows) and zero
  // wbl -> branchless.
  const int cc = wn * 32 + col;              // channel = pair0 % 128
  float p0 = 0.f;
#pragma unroll
  for (int r = 0; r < 16; r++) {
    const int row = (r & 3) + 8 * (r >> 2) + 4 * q;
    p0 += acc[r] * bf2f(wbl[nw][row * 128 + cc]);
  }
  p0 += __shfl_xor(p0, 32);
  if (q == 0) out[pair0] = p0;
}

// ------------------------------------------------------------------
extern "C" void kernel_launch(void* const* d_in, const int* in_sizes, int n_in,
                              void* d_out, int out_size, void* d_ws, size_t ws_size,
                              hipStream_t stream) {
  const float* x  = (const float*)d_in[0];
  const float* y  = (const float*)d_in[1];
  const float* U3 = (const float*)d_in[2];
  const float* U2 = (const float*)d_in[3];
  const float* U1 = (const float*)d_in[4];
  const float* w3 = (const float*)d_in[5];
  const float* w2 = (const float*)d_in[6];
  const float* w1 = (const float*)d_in[7];
  u16*   Sfrag16 = (u16*)d_ws;
  float* out     = (float*)d_out;

  hipLaunchKernelGGL(prep_kernel, dim3(PREP_THREADS / 256), dim3(256), 0, stream,
                     U3, U2, U1, Sfrag16);
  hipLaunchKernelGGL(main_kernel, dim3(BN / 2), dim3(512), 0, stream,
                     x, y, w3, w2, w1, (const uint4*)d_ws, out);
}

// Round 9
// 179.579 us; speedup vs baseline: 1.7991x; 1.0048x over previous
//
#include <hip/hip_runtime.h>
#include <utility>

using u16 = unsigned short;
using u32 = unsigned int;

typedef float  f32x4   __attribute__((ext_vector_type(4)));
typedef float  f32x16  __attribute__((ext_vector_type(16)));
typedef __bf16 bf16x8  __attribute__((ext_vector_type(8)));

#define DI __device__ __forceinline__

// ------------------------------------------------------------------
// Monomial basis under the +8 rotation group (for 32x32x16 MFMA).
// Monomials over x[0..15]: cubic (816), quadratic (136), linear (16).
// Group action: rotation by +8q mod 16 (q=0..1).  Cubic orbits all size
// 2 (parity: 3*8=24 != 0 mod 16) -> 408 reps; quad: 8 fixed orbits
// {a,a+8} + 64 size-2 -> 72 reps (8 dup slots stay null); linear -> 8
// reps.  408+72+8 = 488 = 61 chunks * 8 exactly (no padding).
// Feature slot f = chunk*16 + q*8 + j  <->  rep r = chunk*8 + j,
// monomial = rot_{8q}(rep[r]).  Lane half q = lane>>5 holds x rotated by
// 8q at the address level, so all lanes run identical compile-time code.
// Reps are lex-ordered -> consecutive cubic reps often share the (a,b)
// prefix; prefix products are compile-time-deduped per chunk (round 8).
// ------------------------------------------------------------------
struct RepT { unsigned char a, b, c, t; };   // t: 3=cubic 2=quad 1=linear 0=null
struct Tables8 {
  RepT rep[488];        // compile-time rep list for feature templates
  RepT slotmono[976];   // per feature-slot: SORTED monomial (prep gather); t=0 if dup
  int n3, n2, n1;
};

constexpr int csort3key(int w, int x, int i) {
  int a = w, b = x, c = i, t = 0;
  if (a > b) { t = a; a = b; b = t; }
  if (b > c) { t = b; b = c; c = t; }
  if (a > b) { t = a; a = b; b = t; }
  return (a << 8) | (b << 4) | c;
}
constexpr int csort2key(int a, int b) { return a <= b ? ((a << 4) | b) : ((b << 4) | a); }

constexpr Tables8 build_tables8() {
  Tables8 T = {};
  bool used3[4096] = {};
  bool used2[256] = {};
  int nr = 0;
  // cubic multisets a<=b<=c, canonical = lex-min of {self, +8 rotation}
  for (int a = 0; a < 16; a++) for (int b = a; b < 16; b++) for (int c = b; c < 16; c++) {
    const int key  = (a << 8) | (b << 4) | c;
    const int rkey = csort3key((a + 8) & 15, (b + 8) & 15, (c + 8) & 15);
    if (rkey < key) continue;                 // partner is the canonical one
    for (int q = 0; q < 2; q++) {
      const int kk = q ? rkey : key;
      if (!used3[kk]) {
        used3[kk] = true;
        const int f = (nr >> 3) * 16 + q * 8 + (nr & 7);
        T.slotmono[f].a = (unsigned char)(kk >> 8);
        T.slotmono[f].b = (unsigned char)((kk >> 4) & 15);
        T.slotmono[f].c = (unsigned char)(kk & 15);
        T.slotmono[f].t = 3;
      }
    }
    T.rep[nr].a = (unsigned char)a; T.rep[nr].b = (unsigned char)b;
    T.rep[nr].c = (unsigned char)c; T.rep[nr].t = 3; nr++;
  }
  T.n3 = nr;
  // quadratic multisets a<=b
  for (int a = 0; a < 16; a++) for (int b = a; b < 16; b++) {
    const int key  = (a << 4) | b;
    const int rkey = csort2key((a + 8) & 15, (b + 8) & 15);
    if (rkey < key) continue;
    for (int q = 0; q < 2; q++) {
      const int kk = q ? rkey : key;
      if (!used2[kk]) {                      // fixed orbits: q=1 slot stays null
        used2[kk] = true;
        const int f = (nr >> 3) * 16 + q * 8 + (nr & 7);
        T.slotmono[f].a = (unsigned char)(kk >> 4);
        T.slotmono[f].b = (unsigned char)(kk & 15);
        T.slotmono[f].c = 0;
        T.slotmono[f].t = 2;
      }
    }
    T.rep[nr].a = (unsigned char)a; T.rep[nr].b = (unsigned char)b;
    T.rep[nr].c = 0; T.rep[nr].t = 2; nr++;
  }
  T.n2 = nr;
  // linear: reps 0..7, orbit {a, a+8}
  for (int a = 0; a < 8; a++) {
    for (int q = 0; q < 2; q++) {
      const int f = (nr >> 3) * 16 + q * 8 + (nr & 7);
      T.slotmono[f].a = (unsigned char)((a + 8 * q) & 15);
      T.slotmono[f].b = 0; T.slotmono[f].c = 0; T.slotmono[f].t = 1;
    }
    T.rep[nr].a = (unsigned char)a; T.rep[nr].b = 0; T.rep[nr].c = 0;
    T.rep[nr].t = 1; nr++;
  }
  T.n1 = nr;
  return T;
}

constexpr Tables8 TT8 = build_tables8();
static_assert(TT8.n3 == 408, "cubic rep count");
static_assert(TT8.n2 == 480, "quad rep count");
static_assert(TT8.n1 == 488, "linear rep count");   // 61 chunks * 8, exact

__device__ const Tables8 g_T8 = build_tables8();   // runtime copy for prep kernel

// dims
#define BN 5888
#define CN 128
#define EN 10
#define NCHUNK 61          // 488 reps / 8; K = 976

DI u16 f2bf(float f) { union { __bf16 h; u16 s; } u; u.h = (__bf16)f; return u.s; }
DI float bf2f(u16 v) { union { u32 u; float f; } w; w.u = ((u32)v) << 16; return w.f; }

// ------------------------------------------------------------------
// prep kernel: ONE dispatch, no memset, no atomics.  One thread per
// packed-fragment u16: gathers its monomial's <=6 distinct U-index
// permutations, sums, converts to bf16, writes coalesced.
// Fragment layout (matches main's staging copy exactly):
// uint4 idx = chunk*64 + l; lane l: path = l&31, q = l>>5; u16 j in
// [0,8): feature slot = chunk*16 + q*8 + j.  Paths 28..31 are zero.
// ------------------------------------------------------------------
#define PREP_THREADS (NCHUNK * 64 * 8)     // 31232 u16 = 61 KB

__global__ void prep_kernel(const float* __restrict__ U3, const float* __restrict__ U2,
                            const float* __restrict__ U1, u16* __restrict__ Sfrag16) {
  const int tid = blockIdx.x * 256 + threadIdx.x;
  if (tid >= PREP_THREADS) return;
  const int j = tid & 7, l = (tid >> 3) & 63, chunk = tid >> 9;
  const int path = l & 31, q = l >> 5;
  const RepT m = g_T8.slotmono[chunk * 16 + q * 8 + j];
  float v = 0.f;
  if (m.t == 3 && path < 23) {
    const int a = m.a, b = m.b, d = m.c;
    v = U3[((a * 16 + b) * 16 + d) * 23 + path];
    if (a == b && b == d) {
      // single distinct permutation
    } else if (a == b) {            // (a,a,d): +ada, +daa
      v += U3[((a * 16 + d) * 16 + a) * 23 + path]
         + U3[((d * 16 + a) * 16 + a) * 23 + path];
    } else if (b == d) {            // (a,b,b): +bab, +bba
      v += U3[((b * 16 + a) * 16 + b) * 23 + path]
         + U3[((b * 16 + b) * 16 + a) * 23 + path];
    } else {                        // all distinct: 6 perms
      v += U3[((a * 16 + d) * 16 + b) * 23 + path]
         + U3[((b * 16 + a) * 16 + d) * 23 + path]
         + U3[((b * 16 + d) * 16 + a) * 23 + path]
         + U3[((d * 16 + a) * 16 + b) * 23 + path]
         + U3[((d * 16 + b) * 16 + a) * 23 + path];
    }
  } else if (m.t == 2 && path >= 23 && path < 27) {
    const int k = path - 23, a = m.a, b = m.b;
    v = U2[(a * 16 + b) * 4 + k];
    if (a != b) v += U2[(b * 16 + a) * 4 + k];
  } else if (m.t == 1 && path == 27) {
    v = U1[m.a];
  }
  Sfrag16[tid] = f2bf(v);
}

// ------------------------------------------------------------------
// main kernel (32x32x16 MFMA).  Journal of hard-won constraints:
//  - NEVER demand occupancy beyond the VGPR budget via launch_bounds
//    min-waves (round 0: clamp to 32 VGPR -> 430 MB scratch traffic).
//  - NO sched_barrier (prior round 10: 8x regression).
//  - w-reads block-coalesced once (prior round 5: 990 MB L2 fetch).
//  - Round 2: K-splitting across waves doubles per-wave fixed costs.
//  - Round 4: global A-path -> VGPR 76 (>64 halves wave cap) = 120 us.
//  - Round 5: persistent loop + loop-invariant global A-loads -> LICM
//    spill (WRITE 218 MB, 250 us).  A-path stays ds_read.
//  - Round 6: dual f32x16 acc -> spill (WRITE 28 MB).
//  - Round 7: f32x2/v_pk packing -> spill (WRITE 20.6 MB) despite VALU
//    42.6 us busy; pair-aligned VGPR shapes fragment the allocator.
//    THE ENVELOPE IS: xr[16] + one acc[16] + SCALAR temps.  Nothing
//    wider.
// THIS ROUND: r3 structure + compile-time prefix-shared monomials.
// Cubic reps are lex-ordered; distinct (a,b) prefix products computed
// once per chunk (constexpr dedup), features = pp * x[c].  Cubic muls
// 816 -> ~600 per wave, all scalar v_mul_f32, zero new live state.
// ------------------------------------------------------------------

// first j' <= J in chunk C with the same cubic (a,b) prefix
constexpr int pfirst3(int C, int J) {
  for (int k = 0; k < J; ++k)
    if (TT8.rep[C * 8 + k].t == 3 &&
        TT8.rep[C * 8 + k].a == TT8.rep[C * 8 + J].a &&
        TT8.rep[C * 8 + k].b == TT8.rep[C * 8 + J].b)
      return k;
  return J;
}

template<int C, int J>
DI void bstep(float* pp, const float* xr, bf16x8& r) {
  constexpr RepT rp = TT8.rep[C * 8 + J];
  if constexpr (rp.t == 3) {
    constexpr int pf = pfirst3(C, J);
    if constexpr (pf == J) pp[J] = xr[rp.a] * xr[rp.b];  // new prefix product
    r[J] = (__bf16)(pp[pf] * xr[rp.c]);
  } else if constexpr (rp.t == 2) {
    r[J] = (__bf16)(xr[rp.a] * xr[rp.b]);
  } else if constexpr (rp.t == 1) {
    r[J] = (__bf16)xr[rp.a];
  } else {
    r[J] = (__bf16)0.f;
  }
}

template<int C, int... Js>
DI void bsteps(std::integer_sequence<int, Js...>, float* pp, const float* xr, bf16x8& r) {
  (bstep<C, Js>(pp, xr, r), ...);
}

template<int C>
DI bf16x8 make_B(const float* xr) {
  float pp[8];                 // compile-time-indexed only -> registers (SROA)
  bf16x8 r;
  bsteps<C>(std::make_integer_sequence<int, 8>{}, pp, xr, r);
  return r;
}

// A: 32 paths x 16 K fragment from LDS (one ds_read_b128); B: 8
// features of this pair.  B built before the A-load to keep A's live
// range ds_read -> MFMA.
template<int C>
DI void chunk_step(const uint4* sfl, const float* xr, f32x16& acc) {
  const bf16x8 B = make_B<C>(xr);
  const bf16x8 A = *reinterpret_cast<const bf16x8*>(sfl + C * 64);
  acc = __builtin_amdgcn_mfma_f32_32x32x16_bf16(A, B, acc, 0, 0, 0);
}

template<int... Cs>
DI void run_chunks(std::integer_sequence<int, Cs...>, const uint4* sfl,
                   const float* xr, f32x16& acc) {
  (chunk_step<Cs>(sfl, xr, acc), ...);
}

// xr[v] = x[pair][(v + 8q) & 15] via float4-group rotation (2 groups = 8)
DI void load_xr(const float* __restrict__ x, int pair, int q, float* xr) {
  const float* base = x + pair * 16;
#pragma unroll
  for (int u = 0; u < 4; u++) {
    const int g = (u + 2 * q) & 3;
    const float4 v = *(const float4*)(base + g * 4);
    xr[u * 4 + 0] = v.x;
    xr[u * 4 + 1] = v.y;
    xr[u * 4 + 2] = v.z;
    xr[u * 4 + 3] = v.w;
  }
}

// 512-thread blocks: 8 waves = 2 nodes (4 waves x 32 pairs each).
// LDS = 61 KB sfrag (shared) + 2*8 KB wbl = 77 KB -> 2 blocks/CU.
// launch_bounds (512,4): 4 waves/EU is exactly the LDS-bound occupancy;
// r3-proven spill-free at VGPR 64 + 16 AGPR.
__global__ __launch_bounds__(512, 4) void main_kernel(
    const float* __restrict__ x, const float* __restrict__ y,
    const float* __restrict__ w3, const float* __restrict__ w2, const float* __restrict__ w1,
    const uint4* __restrict__ Sfrag, float* __restrict__ out)
{
  __shared__ uint4 sfrag[NCHUNK * 64];         // 62464 B: S in A-frag order
  __shared__ u16  wbl[2][32 * 128];            // 16384 B: WB[path][c] bf16, per node
  const int tid = threadIdx.x;
  const int node0 = blockIdx.x * 2;

  // stage S: straight uint4 copy (prep already packed bf16 fragments)
  for (int idx = tid; idx < NCHUNK * 64; idx += 512) sfrag[idx] = Sfrag[idx];

  // per-node WB = y[b] @ concat(w3,w2,w1).  256 threads/node:
  // tl = tid&255 -> p = tl>>3 (32 paths), c-16-seg = (tl&7)*16.
  // Rows 28..31: wsrc null -> zeros written (branchless epilogue).
  const int nl = tid >> 8;                     // node-local index 0/1
  const int bnode = node0 + nl;
  {
    const int tl = tid & 255;
    const int p  = tl >> 3;
    const int c0 = (tl & 7) * 16;
    float yv[EN];
#pragma unroll
    for (int e = 0; e < EN; e++) yv[e] = y[bnode * EN + e];
    float acc[16];
#pragma unroll
    for (int m = 0; m < 16; m++) acc[m] = 0.f;
    const float* wsrc = nullptr; int stride = 0;
    if (p < 23)       { wsrc = w3 + p * 128;        stride = 23 * 128; }
    else if (p < 27)  { wsrc = w2 + (p - 23) * 128; stride = 4 * 128; }
    else if (p == 27) { wsrc = w1;                  stride = 128; }
    if (wsrc) {
      for (int e = 0; e < EN; e++) {
        const float* src = wsrc + e * stride + c0;
        const float4 v0 = *(const float4*)(src);
        const float4 v1 = *(const float4*)(src + 4);
        const float4 v2 = *(const float4*)(src + 8);
        const float4 v3 = *(const float4*)(src + 12);
        acc[0]  += yv[e] * v0.x; acc[1]  += yv[e] * v0.y;
        acc[2]  += yv[e] * v0.z; acc[3]  += yv[e] * v0.w;
        acc[4]  += yv[e] * v1.x; acc[5]  += yv[e] * v1.y;
        acc[6]  += yv[e] * v1.z; acc[7]  += yv[e] * v1.w;
        acc[8]  += yv[e] * v2.x; acc[9]  += yv[e] * v2.y;
        acc[10] += yv[e] * v2.z; acc[11] += yv[e] * v2.w;
        acc[12] += yv[e] * v3.x; acc[13] += yv[e] * v3.y;
        acc[14] += yv[e] * v3.z; acc[15] += yv[e] * v3.w;
      }
    }
#pragma unroll
    for (int m = 0; m < 16; m++) wbl[nl][p * 128 + c0 + m] = f2bf(acc[m]);
  }
  __syncthreads();

  // wave handles 32 pairs; 4 waves per node, 2 nodes per block
  const int w = tid >> 6, wn = w & 3, nw = w >> 2;
  const int lane = tid & 63, col = lane & 31, q = lane >> 5;
  const int mnode = node0 + nw;
  const int pair0 = mnode * 128 + wn * 32 + col;

  float xr[16];
  load_xr(x, pair0, q, xr);

  const uint4* sfl = sfrag + lane;
  f32x16 acc = {0.f, 0.f, 0.f, 0.f, 0.f, 0.f, 0.f, 0.f,
                0.f, 0.f, 0.f, 0.f, 0.f, 0.f, 0.f, 0.f};
  run_chunks(std::make_integer_sequence<int, NCHUNK>{}, sfl, xr, acc);

  // epilogue: out[pair] = sum_p D[p][pair] * WB[p][c], reduce over the
  // two lane-halves.  D layout (32x32, m74/m101-verified):
  // col = lane&31 = pair, row = (reg&3) + 8*(reg>>2) + 4*q = path.
  // Rows 28..31 (q=1, reg 12..15) have zero D (zero A-rows) and zero
  // wbl -> branchless.
  const int cc = wn * 32 + col;              // channel = pair0 % 128
  float p0 = 0.f;
#pragma unroll
  for (int r = 0; r < 16; r++) {
    const int row = (r & 3) + 8 * (r >> 2) + 4 * q;
    p0 += acc[r] * bf2f(wbl[nw][row * 128 + cc]);
  }
  p0 += __shfl_xor(p0, 32);
  if (q == 0) out[pair0] = p0;
}

// ------------------------------------------------------------------
extern "C" void kernel_launch(void* const* d_in, const int* in_sizes, int n_in,
                              void* d_out, int out_size, void* d_ws, size_t ws_size,
                              hipStream_t stream) {
  const float* x  = (const float*)d_in[0];
  const float* y  = (const float*)d_in[1];
  const float* U3 = (const float*)d_in[2];
  const float* U2 = (const float*)d_in[3];
  const float* U1 = (const float*)d_in[4];
  const float* w3 = (const float*)d_in[5];
  const float* w2 = (const float*)d_in[6];
  const float* w1 = (const float*)d_in[7];
  u16*   Sfrag16 = (u16*)d_ws;
  float* out     = (float*)d_out;

  hipLaunchKernelGGL(prep_kernel, dim3(PREP_THREADS / 256), dim3(256), 0, stream,
                     U3, U2, U1, Sfrag16);
  hipLaunchKernelGGL(main_kernel, dim3(BN / 2), dim3(512), 0, stream,
                     x, y, w3, w2, w1, (const uint4*)d_ws, out);
}

// Round 10
// 170.405 us; speedup vs baseline: 1.8960x; 1.0538x over previous
//
#include <hip/hip_runtime.h>
#include <utility>

using u16 = unsigned short;
using u32 = unsigned int;

typedef float  f32x4   __attribute__((ext_vector_type(4)));
typedef float  f32x16  __attribute__((ext_vector_type(16)));
typedef __bf16 bf16x8  __attribute__((ext_vector_type(8)));

#define DI __device__ __forceinline__

// ------------------------------------------------------------------
// Monomial basis under the +8 rotation group (for 32x32x16 MFMA).
// Monomials over x[0..15]: cubic (816), quadratic (136), linear (16).
// Group action: rotation by +8q mod 16 (q=0..1).  Cubic orbits all size
// 2 (parity: 3*8=24 != 0 mod 16) -> 408 reps; quad: 8 fixed orbits
// {a,a+8} + 64 size-2 -> 72 reps (8 dup slots stay null); linear -> 8
// reps.  408+72+8 = 488 = 61 chunks * 8 exactly (no padding).
// Feature slot f = chunk*16 + q*8 + j  <->  rep r = chunk*8 + j,
// monomial = rot_{8q}(rep[r]).  Lane half q = lane>>5 holds x rotated by
// 8q at the address level, so all lanes run identical compile-time code.
// Reps are lex-ordered -> consecutive cubic reps often share the (a,b)
// prefix; prefix products are compile-time-deduped per chunk (round 8).
// ------------------------------------------------------------------
struct RepT { unsigned char a, b, c, t; };   // t: 3=cubic 2=quad 1=linear 0=null
struct Tables8 {
  RepT rep[488];        // compile-time rep list for feature templates
  RepT slotmono[976];   // per feature-slot: SORTED monomial (prep gather); t=0 if dup
  int n3, n2, n1;
};

constexpr int csort3key(int w, int x, int i) {
  int a = w, b = x, c = i, t = 0;
  if (a > b) { t = a; a = b; b = t; }
  if (b > c) { t = b; b = c; c = t; }
  if (a > b) { t = a; a = b; b = t; }
  return (a << 8) | (b << 4) | c;
}
constexpr int csort2key(int a, int b) { return a <= b ? ((a << 4) | b) : ((b << 4) | a); }

constexpr Tables8 build_tables8() {
  Tables8 T = {};
  bool used3[4096] = {};
  bool used2[256] = {};
  int nr = 0;
  // cubic multisets a<=b<=c, canonical = lex-min of {self, +8 rotation}
  for (int a = 0; a < 16; a++) for (int b = a; b < 16; b++) for (int c = b; c < 16; c++) {
    const int key  = (a << 8) | (b << 4) | c;
    const int rkey = csort3key((a + 8) & 15, (b + 8) & 15, (c + 8) & 15);
    if (rkey < key) continue;                 // partner is the canonical one
    for (int q = 0; q < 2; q++) {
      const int kk = q ? rkey : key;
      if (!used3[kk]) {
        used3[kk] = true;
        const int f = (nr >> 3) * 16 + q * 8 + (nr & 7);
        T.slotmono[f].a = (unsigned char)(kk >> 8);
        T.slotmono[f].b = (unsigned char)((kk >> 4) & 15);
        T.slotmono[f].c = (unsigned char)(kk & 15);
        T.slotmono[f].t = 3;
      }
    }
    T.rep[nr].a = (unsigned char)a; T.rep[nr].b = (unsigned char)b;
    T.rep[nr].c = (unsigned char)c; T.rep[nr].t = 3; nr++;
  }
  T.n3 = nr;
  // quadratic multisets a<=b
  for (int a = 0; a < 16; a++) for (int b = a; b < 16; b++) {
    const int key  = (a << 4) | b;
    const int rkey = csort2key((a + 8) & 15, (b + 8) & 15);
    if (rkey < key) continue;
    for (int q = 0; q < 2; q++) {
      const int kk = q ? rkey : key;
      if (!used2[kk]) {                      // fixed orbits: q=1 slot stays null
        used2[kk] = true;
        const int f = (nr >> 3) * 16 + q * 8 + (nr & 7);
        T.slotmono[f].a = (unsigned char)(kk >> 4);
        T.slotmono[f].b = (unsigned char)(kk & 15);
        T.slotmono[f].c = 0;
        T.slotmono[f].t = 2;
      }
    }
    T.rep[nr].a = (unsigned char)a; T.rep[nr].b = (unsigned char)b;
    T.rep[nr].c = 0; T.rep[nr].t = 2; nr++;
  }
  T.n2 = nr;
  // linear: reps 0..7, orbit {a, a+8}
  for (int a = 0; a < 8; a++) {
    for (int q = 0; q < 2; q++) {
      const int f = (nr >> 3) * 16 + q * 8 + (nr & 7);
      T.slotmono[f].a = (unsigned char)((a + 8 * q) & 15);
      T.slotmono[f].b = 0; T.slotmono[f].c = 0; T.slotmono[f].t = 1;
    }
    T.rep[nr].a = (unsigned char)a; T.rep[nr].b = 0; T.rep[nr].c = 0;
    T.rep[nr].t = 1; nr++;
  }
  T.n1 = nr;
  return T;
}

constexpr Tables8 TT8 = build_tables8();
static_assert(TT8.n3 == 408, "cubic rep count");
static_assert(TT8.n2 == 480, "quad rep count");
static_assert(TT8.n1 == 488, "linear rep count");   // 61 chunks * 8, exact

__device__ const Tables8 g_T8 = build_tables8();   // runtime copy for prep kernel

// dims
#define BN 5888
#define CN 128
#define EN 10
#define NCHUNK 61          // 488 reps / 8; K = 976

DI u16 f2bf(float f) { union { __bf16 h; u16 s; } u; u.h = (__bf16)f; return u.s; }
DI float bf2f(u16 v) { union { u32 u; float f; } w; w.u = ((u32)v) << 16; return w.f; }

// ------------------------------------------------------------------
// prep kernel: ONE dispatch, no memset, no atomics.  One thread per
// packed-fragment u16: gathers its monomial's <=6 distinct U-index
// permutations, sums, converts to bf16, writes coalesced.
// Fragment layout (matches main's staging copy exactly):
// uint4 idx = chunk*64 + l; lane l: path = l&31, q = l>>5; u16 j in
// [0,8): feature slot = chunk*16 + q*8 + j.  Paths 28..31 are zero.
// ------------------------------------------------------------------
#define PREP_THREADS (NCHUNK * 64 * 8)     // 31232 u16 = 61 KB

__global__ void prep_kernel(const float* __restrict__ U3, const float* __restrict__ U2,
                            const float* __restrict__ U1, u16* __restrict__ Sfrag16) {
  const int tid = blockIdx.x * 256 + threadIdx.x;
  if (tid >= PREP_THREADS) return;
  const int j = tid & 7, l = (tid >> 3) & 63, chunk = tid >> 9;
  const int path = l & 31, q = l >> 5;
  const RepT m = g_T8.slotmono[chunk * 16 + q * 8 + j];
  float v = 0.f;
  if (m.t == 3 && path < 23) {
    const int a = m.a, b = m.b, d = m.c;
    v = U3[((a * 16 + b) * 16 + d) * 23 + path];
    if (a == b && b == d) {
      // single distinct permutation
    } else if (a == b) {            // (a,a,d): +ada, +daa
      v += U3[((a * 16 + d) * 16 + a) * 23 + path]
         + U3[((d * 16 + a) * 16 + a) * 23 + path];
    } else if (b == d) {            // (a,b,b): +bab, +bba
      v += U3[((b * 16 + a) * 16 + b) * 23 + path]
         + U3[((b * 16 + b) * 16 + a) * 23 + path];
    } else {                        // all distinct: 6 perms
      v += U3[((a * 16 + d) * 16 + b) * 23 + path]
         + U3[((b * 16 + a) * 16 + d) * 23 + path]
         + U3[((b * 16 + d) * 16 + a) * 23 + path]
         + U3[((d * 16 + a) * 16 + b) * 23 + path]
         + U3[((d * 16 + b) * 16 + a) * 23 + path];
    }
  } else if (m.t == 2 && path >= 23 && path < 27) {
    const int k = path - 23, a = m.a, b = m.b;
    v = U2[(a * 16 + b) * 4 + k];
    if (a != b) v += U2[(b * 16 + a) * 4 + k];
  } else if (m.t == 1 && path == 27) {
    v = U1[m.a];
  }
  Sfrag16[tid] = f2bf(v);
}

// ------------------------------------------------------------------
// main kernel (32x32x16 MFMA).  Journal of hard-won constraints:
//  - NEVER demand occupancy beyond the VGPR budget via launch_bounds
//    min-waves (round 0: clamp to 32 VGPR -> 430 MB scratch traffic).
//  - NO sched_barrier (prior round 10: 8x regression).
//  - w-reads block-coalesced once (prior round 5: 990 MB L2 fetch).
//  - Round 2: K-splitting across waves doubles per-wave fixed costs.
//  - Round 4: global A-path -> VGPR 76 (>64 halves wave cap) = 120 us.
//  - Round 5: persistent loop + loop-invariant global A-loads -> LICM
//    spill (WRITE 218 MB).  A-path stays ds_read.
//  - Rounds 6/7: dual acc / f32x2 v_pk shapes -> spill.  THE ENVELOPE
//    IS: xr[16] + one acc[16] + SCALAR temps.
//  - Round 8: prefix-dedup of muls = neutral -> B-build cost is NOT
//    the multiplies; it's the f32->bf16 convert+insert packing (~2-3
//    instr/element).
// THIS ROUND: pack B via inline-asm v_cvt_pk_bf16_f32 (1 instr per
// bf16 PAIR, same RNE rounding as scalar cast -> bit-identical).
// Hot-loop VALU ~1800 -> ~1100 instr/wave.
// ------------------------------------------------------------------

// first j' <= J in chunk C with the same cubic (a,b) prefix
constexpr int pfirst3(int C, int J) {
  for (int k = 0; k < J; ++k)
    if (TT8.rep[C * 8 + k].t == 3 &&
        TT8.rep[C * 8 + k].a == TT8.rep[C * 8 + J].a &&
        TT8.rep[C * 8 + k].b == TT8.rep[C * 8 + J].b)
      return k;
  return J;
}

// feature value in f32 (prefix products deduped per chunk)
template<int C, int J>
DI float featv(float* pp, const float* xr) {
  constexpr RepT rp = TT8.rep[C * 8 + J];
  if constexpr (rp.t == 3) {
    constexpr int pf = pfirst3(C, J);
    if constexpr (pf == J) pp[J] = xr[rp.a] * xr[rp.b];  // new prefix product
    return pp[pf] * xr[rp.c];
  } else if constexpr (rp.t == 2) {
    return xr[rp.a] * xr[rp.b];
  } else if constexpr (rp.t == 1) {
    return xr[rp.a];
  } else {
    return 0.f;
  }
}

// one u32 = two bf16 (RNE, identical to scalar (__bf16) cast); src0->lo16
DI u32 cvtpk(float lo, float hi) {
  u32 r;
  asm("v_cvt_pk_bf16_f32 %0, %1, %2" : "=v"(r) : "v"(lo), "v"(hi));
  return r;
}

template<int C>
DI bf16x8 make_B(const float* xr) {
  float pp[8];                 // compile-time-indexed only -> registers (SROA)
  float f[8];
  f[0] = featv<C, 0>(pp, xr);
  f[1] = featv<C, 1>(pp, xr);
  f[2] = featv<C, 2>(pp, xr);
  f[3] = featv<C, 3>(pp, xr);
  f[4] = featv<C, 4>(pp, xr);
  f[5] = featv<C, 5>(pp, xr);
  f[6] = featv<C, 6>(pp, xr);
  f[7] = featv<C, 7>(pp, xr);
  union { u32 u[4]; bf16x8 b; } r;
  r.u[0] = cvtpk(f[0], f[1]);
  r.u[1] = cvtpk(f[2], f[3]);
  r.u[2] = cvtpk(f[4], f[5]);
  r.u[3] = cvtpk(f[6], f[7]);
  return r.b;
}

// A: 32 paths x 16 K fragment from LDS (one ds_read_b128); B: 8
// features of this pair.  B built before the A-load to keep A's live
// range ds_read -> MFMA.
template<int C>
DI void chunk_step(const uint4* sfl, const float* xr, f32x16& acc) {
  const bf16x8 B = make_B<C>(xr);
  const bf16x8 A = *reinterpret_cast<const bf16x8*>(sfl + C * 64);
  acc = __builtin_amdgcn_mfma_f32_32x32x16_bf16(A, B, acc, 0, 0, 0);
}

template<int... Cs>
DI void run_chunks(std::integer_sequence<int, Cs...>, const uint4* sfl,
                   const float* xr, f32x16& acc) {
  (chunk_step<Cs>(sfl, xr, acc), ...);
}

// xr[v] = x[pair][(v + 8q) & 15] via float4-group rotation (2 groups = 8)
DI void load_xr(const float* __restrict__ x, int pair, int q, float* xr) {
  const float* base = x + pair * 16;
#pragma unroll
  for (int u = 0; u < 4; u++) {
    const int g = (u + 2 * q) & 3;
    const float4 v = *(const float4*)(base + g * 4);
    xr[u * 4 + 0] = v.x;
    xr[u * 4 + 1] = v.y;
    xr[u * 4 + 2] = v.z;
    xr[u * 4 + 3] = v.w;
  }
}

// 512-thread blocks: 8 waves = 2 nodes (4 waves x 32 pairs each).
// LDS = 61 KB sfrag (shared) + 2*8 KB wbl = 77 KB -> 2 blocks/CU.
// launch_bounds (512,4): 4 waves/EU is exactly the LDS-bound occupancy;
// r3-proven spill-free at VGPR 64 + 16 AGPR.
__global__ __launch_bounds__(512, 4) void main_kernel(
    const float* __restrict__ x, const float* __restrict__ y,
    const float* __restrict__ w3, const float* __restrict__ w2, const float* __restrict__ w1,
    const uint4* __restrict__ Sfrag, float* __restrict__ out)
{
  __shared__ uint4 sfrag[NCHUNK * 64];         // 62464 B: S in A-frag order
  __shared__ u16  wbl[2][32 * 128];            // 16384 B: WB[path][c] bf16, per node
  const int tid = threadIdx.x;
  const int node0 = blockIdx.x * 2;

  // stage S: straight uint4 copy (prep already packed bf16 fragments)
  for (int idx = tid; idx < NCHUNK * 64; idx += 512) sfrag[idx] = Sfrag[idx];

  // per-node WB = y[b] @ concat(w3,w2,w1).  256 threads/node:
  // tl = tid&255 -> p = tl>>3 (32 paths), c-16-seg = (tl&7)*16.
  // Rows 28..31: wsrc null -> zeros written (branchless epilogue).
  const int nl = tid >> 8;                     // node-local index 0/1
  const int bnode = node0 + nl;
  {
    const int tl = tid & 255;
    const int p  = tl >> 3;
    const int c0 = (tl & 7) * 16;
    float yv[EN];
#pragma unroll
    for (int e = 0; e < EN; e++) yv[e] = y[bnode * EN + e];
    float acc[16];
#pragma unroll
    for (int m = 0; m < 16; m++) acc[m] = 0.f;
    const float* wsrc = nullptr; int stride = 0;
    if (p < 23)       { wsrc = w3 + p * 128;        stride = 23 * 128; }
    else if (p < 27)  { wsrc = w2 + (p - 23) * 128; stride = 4 * 128; }
    else if (p == 27) { wsrc = w1;                  stride = 128; }
    if (wsrc) {
      for (int e = 0; e < EN; e++) {
        const float* src = wsrc + e * stride + c0;
        const float4 v0 = *(const float4*)(src);
        const float4 v1 = *(const float4*)(src + 4);
        const float4 v2 = *(const float4*)(src + 8);
        const float4 v3 = *(const float4*)(src + 12);
        acc[0]  += yv[e] * v0.x; acc[1]  += yv[e] * v0.y;
        acc[2]  += yv[e] * v0.z; acc[3]  += yv[e] * v0.w;
        acc[4]  += yv[e] * v1.x; acc[5]  += yv[e] * v1.y;
        acc[6]  += yv[e] * v1.z; acc[7]  += yv[e] * v1.w;
        acc[8]  += yv[e] * v2.x; acc[9]  += yv[e] * v2.y;
        acc[10] += yv[e] * v2.z; acc[11] += yv[e] * v2.w;
        acc[12] += yv[e] * v3.x; acc[13] += yv[e] * v3.y;
        acc[14] += yv[e] * v3.z; acc[15] += yv[e] * v3.w;
      }
    }
#pragma unroll
    for (int m = 0; m < 16; m++) wbl[nl][p * 128 + c0 + m] = f2bf(acc[m]);
  }
  __syncthreads();

  // wave handles 32 pairs; 4 waves per node, 2 nodes per block
  const int w = tid >> 6, wn = w & 3, nw = w >> 2;
  const int lane = tid & 63, col = lane & 31, q = lane >> 5;
  const int mnode = node0 + nw;
  const int pair0 = mnode * 128 + wn * 32 + col;

  float xr[16];
  load_xr(x, pair0, q, xr);

  const uint4* sfl = sfrag + lane;
  f32x16 acc = {0.f, 0.f, 0.f, 0.f, 0.f, 0.f, 0.f, 0.f,
                0.f, 0.f, 0.f, 0.f, 0.f, 0.f, 0.f, 0.f};
  run_chunks(std::make_integer_sequence<int, NCHUNK>{}, sfl, xr, acc);

  // epilogue: out[pair] = sum_p D[p][pair] * WB[p][c], reduce over the
  // two lane-halves.  D layout (32x32, m74/m101-verified):
  // col = lane&31 = pair, row = (reg&3) + 8*(reg>>2) + 4*q = path.
  // Rows 28..31 (q=1, reg 12..15) have zero D (zero A-rows) and zero
  // wbl -> branchless.
  const int cc = wn * 32 + col;              // channel = pair0 % 128
  float p0 = 0.f;
#pragma unroll
  for (int r = 0; r < 16; r++) {
    const int row = (r & 3) + 8 * (r >> 2) + 4 * q;
    p0 += acc[r] * bf2f(wbl[nw][row * 128 + cc]);
  }
  p0 += __shfl_xor(p0, 32);
  if (q == 0) out[pair0] = p0;
}

// ------------------------------------------------------------------
extern "C" void kernel_launch(void* const* d_in, const int* in_sizes, int n_in,
                              void* d_out, int out_size, void* d_ws, size_t ws_size,
                              hipStream_t stream) {
  const float* x  = (const float*)d_in[0];
  const float* y  = (const float*)d_in[1];
  const float* U3 = (const float*)d_in[2];
  const float* U2 = (const float*)d_in[3];
  const float* U1 = (const float*)d_in[4];
  const float* w3 = (const float*)d_in[5];
  const float* w2 = (const float*)d_in[6];
  const float* w1 = (const float*)d_in[7];
  u16*   Sfrag16 = (u16*)d_ws;
  float* out     = (float*)d_out;

  hipLaunchKernelGGL(prep_kernel, dim3(PREP_THREADS / 256), dim3(256), 0, stream,
                     U3, U2, U1, Sfrag16);
  hipLaunchKernelGGL(main_kernel, dim3(BN / 2), dim3(512), 0, stream,
                     x, y, w3, w2, w1, (const uint4*)d_ws, out);
}